// Round 9
// baseline (196.470 us; speedup 1.0000x reference)
//
#include <hip/hip_runtime.h>

typedef _Float16 half8 __attribute__((ext_vector_type(8)));
typedef float floatx4 __attribute__((ext_vector_type(4)));

#define SEQ 2048
#define DMODEL 1024
#define NHEADS 16
#define HEADDIM 64
#define PW 5120   // proj row width: q|k|v|kg|vg

// ---------------- fused prep: x fp32->fp16 + 6 weight transposes ----------------
__global__ __launch_bounds__(256) void k_prep(
    const float* __restrict__ x,
    const float* __restrict__ w0, const float* __restrict__ w1, const float* __restrict__ w2,
    const float* __restrict__ w3, const float* __restrict__ w4, const float* __restrict__ w5,
    _Float16* __restrict__ xh, _Float16* __restrict__ wcat, _Float16* __restrict__ wot) {
  const int tid = threadIdx.x;
  const int b = blockIdx.x;
  if (b < 1024) {
    int base = b * 2048 + tid * 8;
    floatx4 f0 = *(const floatx4*)(x + base);
    floatx4 f1 = *(const floatx4*)(x + base + 4);
    half8 h;
    #pragma unroll
    for (int e = 0; e < 4; ++e) { h[e] = (_Float16)f0[e]; h[e + 4] = (_Float16)f1[e]; }
    *(half8*)(xh + base) = h;
    return;
  }
  __shared__ _Float16 T[64][72];
  int t = b - 1024;
  int z = t >> 8;
  int tile = t & 255;
  int k0 = (tile >> 4) * 64, n0 = (tile & 15) * 64;
  const float* W = (z == 0) ? w0 : (z == 1) ? w1 : (z == 2) ? w2
                 : (z == 3) ? w3 : (z == 4) ? w4 : w5;
  _Float16* dst = (z < 5) ? (wcat + (size_t)z * 1024 * 1024) : wot;

  int lr = tid >> 2, c0 = (tid & 3) * 16;
  #pragma unroll
  for (int i = 0; i < 4; ++i) {
    floatx4 f = *(const floatx4*)(W + (size_t)(k0 + lr) * DMODEL + n0 + c0 + i * 4);
    #pragma unroll
    for (int e = 0; e < 4; ++e) T[c0 + i * 4 + e][lr] = (_Float16)f[e];
  }
  __syncthreads();
  int nr = tid >> 2, s0 = (tid & 3) * 16;
  #pragma unroll
  for (int i = 0; i < 2; ++i) {
    half8 h = *(const half8*)&T[nr][s0 + i * 8];
    *(half8*)(dst + (size_t)(n0 + nr) * DMODEL + k0 + s0 + i * 8) = h;
  }
}

// ---------------- 128x128 MFMA GEMM, BK=128, global_load_lds + XOR swizzle ----------------
// SPARSE (proj path): 400 blocks — b<384 full q|k|v; b>=384 kg|vg at m0=0 only.
// HALF_OUT: fp16 to Cv (+ fused RoPE for n0<2048). !HALF_OUT: fp32 split-K partials.
template <bool HALF_OUT, bool FUSE_ROPE, bool SPARSE>
__global__ __launch_bounds__(256, 2) void k_gemm128b(
    const _Float16* __restrict__ A, const _Float16* __restrict__ Bt,
    void* __restrict__ Cv, float* __restrict__ Cp0, float* __restrict__ Cp1,
    const float* __restrict__ cos_t, const float* __restrict__ sin_t,
    const int* __restrict__ pos, int M, int N, int K, int kLen) {
  __shared__ _Float16 As[128][128];
  __shared__ _Float16 Bs[128][128];
  const int tid = threadIdx.x;
  const int lane = tid & 63;
  const int w = tid >> 6;
  const int wm = (w >> 1) * 64;
  const int wn = (w & 1) * 64;
  const int l15 = lane & 15;
  const int q4 = lane >> 4;
  int m0, n0, kStart;
  if (SPARSE) {
    int b = blockIdx.x;
    if (b < 384) { m0 = (b & 15) * 128; n0 = (b >> 4) * 128; }
    else         { m0 = 0;              n0 = 3072 + (b - 384) * 128; }
    kStart = 0;
  } else {
    m0 = blockIdx.x * 128;
    n0 = blockIdx.y * 128;
    kStart = blockIdx.z * kLen;
  }

  floatx4 acc[4][4];
  #pragma unroll
  for (int i = 0; i < 4; ++i)
    #pragma unroll
    for (int j = 0; j < 4; ++j) acc[i][j] = (floatx4){0.f, 0.f, 0.f, 0.f};

  _Float16* asBase = &As[0][0];
  _Float16* bsBase = &Bs[0][0];
  const int swz = l15 & 7;

  for (int k0 = kStart; k0 < kStart + kLen; k0 += 128) {
    __syncthreads();
    #pragma unroll
    for (int it = 0; it < 8; ++it) {
      int c = it * 256 + tid;
      int r = c >> 4, cc = c & 15;
      int g = cc ^ (r & 7);
      __builtin_amdgcn_global_load_lds(
          (const __attribute__((address_space(1))) void*)(A + (size_t)(m0 + r) * K + k0 + g * 8),
          (__attribute__((address_space(3))) void*)(asBase + (it * 256 + w * 64) * 8),
          16, 0, 0);
      __builtin_amdgcn_global_load_lds(
          (const __attribute__((address_space(1))) void*)(Bt + (size_t)(n0 + r) * K + k0 + g * 8),
          (__attribute__((address_space(3))) void*)(bsBase + (it * 256 + w * 64) * 8),
          16, 0, 0);
    }
    __syncthreads();

    #pragma unroll
    for (int kk = 0; kk < 4; ++kk) {
      int q = kk * 4 + q4;
      half8 af[4], bf[4];
      #pragma unroll
      for (int t = 0; t < 4; ++t) {
        int ar = wm + t * 16 + l15;
        af[t] = *(const half8*)(asBase + (size_t)ar * 128 + ((q ^ swz) * 8));
        int br = wn + t * 16 + l15;
        bf[t] = *(const half8*)(bsBase + (size_t)br * 128 + ((q ^ swz) * 8));
      }
      #pragma unroll
      for (int i = 0; i < 4; ++i)
        #pragma unroll
        for (int j = 0; j < 4; ++j)
          acc[i][j] = __builtin_amdgcn_mfma_f32_16x16x32_f16(af[i], bf[j], acc[i][j], 0, 0, 0);
    }
  }

  float* P = HALF_OUT ? nullptr : ((!SPARSE && blockIdx.z) ? Cp1 : Cp0);
  #pragma unroll
  for (int tm = 0; tm < 4; ++tm) {
    #pragma unroll
    for (int r = 0; r < 4; ++r) {
      int row = m0 + wm + tm * 16 + q4 * 4 + r;
      float v[4];
      #pragma unroll
      for (int tn = 0; tn < 4; ++tn) v[tn] = acc[tm][tn][r];
      if (FUSE_ROPE && n0 < 2048) {
        int p = pos[row];
        #pragma unroll
        for (int tn = 0; tn < 2; ++tn) {
          int d = tn * 16 + l15;
          float a = acc[tm][tn][r];
          float bvv = acc[tm][tn + 2][r];
          float c1 = cos_t[p * 64 + d],      s1 = sin_t[p * 64 + d];
          float c2 = cos_t[p * 64 + d + 32], s2 = sin_t[p * 64 + d + 32];
          v[tn]     = a * c1 - bvv * s1;
          v[tn + 2] = bvv * c2 + a * s2;
        }
      }
      #pragma unroll
      for (int tn = 0; tn < 4; ++tn) {
        int col = n0 + wn + tn * 16 + l15;
        if (HALF_OUT)
          ((_Float16*)Cv)[(size_t)row * N + col] = (_Float16)v[tn];
        else
          P[(size_t)row * N + col] = v[tn];
      }
    }
  }
}

// ---------------- split-K reduce: out = p0 + p1 (fp32) ----------------
__global__ __launch_bounds__(256) void k_reduce(const float* __restrict__ p0,
                                                const float* __restrict__ p1,
                                                float* __restrict__ out) {
  int i = (blockIdx.x * 256 + threadIdx.x) * 4;
  floatx4 a = *(const floatx4*)(p0 + i);
  floatx4 b = *(const floatx4*)(p1 + i);
  *(floatx4*)(out + i) = a + b;
}

// ---------------- merged attention (R6 structure, lean LDS): BM=128, 6 chunks of 64 ----------
// Changes vs R6 (both independently proven safe):
//  - Q frags + global-attn pass read Q DIRECT from global (R8 idiom) -> no Qs LDS (-18 KB),
//    total LDS ~40 KB -> 4 blocks/CU.
//  - V^T layout grouped-pad addr(d,j) = d*72 + (d>>3)*8 + j: 8-row group stride 292 words
//    = 4 mod 32 -> scatter writes tile all 32 banks (R6/R8 layout was 8-way conflicted).
__global__ __launch_bounds__(256, 4) void k_attn(const _Float16* __restrict__ proj,
                                                 _Float16* __restrict__ out) {
  const int tid = threadIdx.x;
  const int hb = blockIdx.y * 64;

  if (blockIdx.x >= 14) {
    // ---- early rows (absorbed-1e9: uniform average over in-window global cols) ----
    const int i = (blockIdx.x - 14) * 4 + (tid >> 6);
    const int lane = tid & 63;
    const float scale = 0.125f;
    float qv = (float)proj[(size_t)i * PW + hb + lane];
    float sg[4];
    #pragma unroll
    for (int g = 0; g < 4; ++g) {
      float kgv = (float)proj[(size_t)g * PW + 3072 + hb + lane];
      float v = qv * kgv;
      #pragma unroll
      for (int off = 32; off; off >>= 1) v += __shfl_xor(v, off, 64);
      sg[g] = v * scale;
    }
    float mg = fmaxf(fmaxf(sg[0], sg[1]), fmaxf(sg[2], sg[3]));
    float dg = 0.f, og = 0.f;
    #pragma unroll
    for (int g = 0; g < 4; ++g) {
      float p = __expf(sg[g] - mg);
      dg += p;
      og += p * (float)proj[(size_t)g * PW + 4096 + hb + lane];
    }
    og /= dg;
    int jmin = (i >= 256) ? (i - 256) : 0;
    int jmax = (i < 3) ? i : 3;
    float acc = 0.f;
    for (int j = jmin; j <= jmax; ++j)
      acc += (float)proj[(size_t)j * PW + 2048 + hb + lane];
    float ol = acc / (float)(jmax - jmin + 1);
    out[(size_t)i * DMODEL + hb + lane] = (_Float16)(ol + og);
    return;
  }

  const int i0 = 256 + blockIdx.x * 128;
  const int jlo = i0 - 256;
  const int lane = tid & 63;
  const int w = tid >> 6;
  const int l15 = lane & 15;
  const int q4 = lane >> 4;

  __shared__ _Float16 Kc[64][72];          //  9.0 KB
  __shared__ _Float16 VtcB[64 * 72 + 64];  //  9.1 KB grouped-pad layout
  __shared__ _Float16 Ps[128][72];         // 18.0 KB
  __shared__ _Float16 kg_s[4][64];
  __shared__ _Float16 vg_s[4][64];
  __shared__ float svg_s[64];
  __shared__ float pg_s[4][128];
  #define VTI(d, j) ((d) * 72 + ((d) >> 3) * 8 + (j))

  // ---- stage global k/v + sum of in-window-zero-score v rows ----
  {
    int g = tid >> 6, c2 = tid & 63;
    kg_s[g][c2] = proj[(size_t)g * PW + 3072 + hb + c2];
    vg_s[g][c2] = proj[(size_t)g * PW + 4096 + hb + c2];
    if (tid < 64) {
      float s = 0.f;
      #pragma unroll
      for (int g2 = 0; g2 < 4; ++g2) s += (float)proj[(size_t)g2 * PW + 2048 + hb + tid];
      svg_s[tid] = s;
    }
  }
  __syncthreads();

  // ---- global-attention probabilities for 128 rows (Q direct from global, R8 idiom) ----
  #pragma unroll
  for (int pass = 0; pass < 2; ++pass) {
    int ro = pass * 64 + w * 16 + (lane >> 2);
    int part = lane & 3;
    const _Float16* qrow = proj + (size_t)(i0 + ro) * PW + hb + part * 16;
    float sg[4];
    #pragma unroll
    for (int g = 0; g < 4; ++g) {
      float acc = 0.f;
      #pragma unroll
      for (int u = 0; u < 16; ++u)
        acc += (float)qrow[u] * (float)kg_s[g][part * 16 + u];
      acc += __shfl_xor(acc, 1, 64);
      acc += __shfl_xor(acc, 2, 64);
      sg[g] = acc * 0.125f;
    }
    float mg = fmaxf(fmaxf(sg[0], sg[1]), fmaxf(sg[2], sg[3]));
    float dg = 0.f;
    #pragma unroll
    for (int g = 0; g < 4; ++g) dg += __expf(sg[g] - mg);
    pg_s[part][ro] = __expf(sg[part] - mg) / dg;
  }

  // Q A-frags direct from global (wave-private rows, registers only)
  half8 qf[2][2];
  #pragma unroll
  for (int rg = 0; rg < 2; ++rg) {
    const _Float16* qp = proj + (size_t)(i0 + w * 32 + rg * 16 + l15) * PW + hb;
    qf[rg][0] = *(const half8*)(qp + q4 * 8);
    qf[rg][1] = *(const half8*)(qp + 32 + q4 * 8);
  }

  float m_r[2][4], l_r[2][4];
  floatx4 oacc[2][4];
  #pragma unroll
  for (int rg = 0; rg < 2; ++rg)
    #pragma unroll
    for (int cb = 0; cb < 4; ++cb) {
      oacc[rg][cb] = (floatx4){0.f, 0.f, 0.f, 0.f};
      m_r[rg][cb] = 0.f;
      l_r[rg][cb] = 4.f;   // 4 global cols with fp32 score exactly 0
    }

  for (int cc = 0; cc < 6; ++cc) {
    const int jbase = jlo + cc * 64;
    __syncthreads();  // prior-iter Kc/Vtc reads done
    // K chunk: 64 rows x 64 halfs, plain half8 loads (conflict-free: groups tile banks)
    #pragma unroll
    for (int rep = 0; rep < 2; ++rep) {
      int c = tid + rep * 256;
      int r = c >> 3, q = c & 7;
      *(half8*)&Kc[r][q * 8] =
          *(const half8*)(proj + (size_t)(jbase + r) * PW + 1024 + hb + q * 8);
    }
    // V chunk transposed: half8 global loads, grouped-pad scalar scatter (conflict-free)
    #pragma unroll
    for (int it = 0; it < 2; ++it) {
      int idx = it * 256 + tid;
      int j = (idx & 7) + ((idx >> 6) << 3);
      int d0 = ((idx >> 3) & 7) * 8;
      half8 vv = *(const half8*)(proj + (size_t)(jbase + j) * PW + 2048 + hb + d0);
      #pragma unroll
      for (int e = 0; e < 8; ++e) VtcB[VTI(d0 + e, j)] = vv[e];
    }
    __syncthreads();

    #pragma unroll
    for (int rg = 0; rg < 2; ++rg) {
      // QK^T: 4 col-blocks of 16
      float sc[4][4];
      #pragma unroll
      for (int cb = 0; cb < 4; ++cb) {
        half8 b0 = *(const half8*)&Kc[cb * 16 + l15][q4 * 8];
        half8 b1 = *(const half8*)&Kc[cb * 16 + l15][32 + q4 * 8];
        floatx4 a = (floatx4){0.f, 0.f, 0.f, 0.f};
        a = __builtin_amdgcn_mfma_f32_16x16x32_f16(qf[rg][0], b0, a, 0, 0, 0);
        a = __builtin_amdgcn_mfma_f32_16x16x32_f16(qf[rg][1], b1, a, 0, 0, 0);
        #pragma unroll
        for (int r = 0; r < 4; ++r) sc[cb][r] = a[r];
      }

      // mask + online softmax
      #pragma unroll
      for (int r = 0; r < 4; ++r) {
        int ri = w * 32 + rg * 16 + q4 * 4 + r;
        float rowmax = -1e30f;
        #pragma unroll
        for (int cb = 0; cb < 4; ++cb) {
          int jjg = cc * 64 + cb * 16 + l15;
          bool valid = (jjg >= ri) && (jjg <= ri + 256);
          float s = valid ? sc[cb][r] * 0.125f : -1e30f;
          sc[cb][r] = s;
          rowmax = fmaxf(rowmax, s);
        }
        #pragma unroll
        for (int off = 1; off < 16; off <<= 1)
          rowmax = fmaxf(rowmax, __shfl_xor(rowmax, off, 64));
        float m_new = fmaxf(m_r[rg][r], rowmax);
        float alpha = __expf(m_r[rg][r] - m_new);
        float rs = 0.f;
        #pragma unroll
        for (int cb = 0; cb < 4; ++cb) {
          float p = __expf(sc[cb][r] - m_new);
          Ps[ri][cb * 16 + l15] = (_Float16)p;
          rs += p;
        }
        #pragma unroll
        for (int off = 1; off < 16; off <<= 1) rs += __shfl_xor(rs, off, 64);
        l_r[rg][r] = l_r[rg][r] * alpha + rs;
        m_r[rg][r] = m_new;
        #pragma unroll
        for (int cb = 0; cb < 4; ++cb) oacc[rg][cb][r] *= alpha;
      }

      // PV: A=P (own rows, same-wave), B=V^T (grouped-pad reads, 16B-aligned)
      int prow = w * 32 + rg * 16 + l15;
      half8 pf0 = *(const half8*)&Ps[prow][q4 * 8];
      half8 pf1 = *(const half8*)&Ps[prow][32 + q4 * 8];
      #pragma unroll
      for (int cb = 0; cb < 4; ++cb) {
        int vd = cb * 16 + l15;
        half8 v0 = *(const half8*)&VtcB[VTI(vd, 0) + q4 * 8];
        half8 v1 = *(const half8*)&VtcB[VTI(vd, 0) + 32 + q4 * 8];
        oacc[rg][cb] = __builtin_amdgcn_mfma_f32_16x16x32_f16(pf0, v0, oacc[rg][cb], 0, 0, 0);
        oacc[rg][cb] = __builtin_amdgcn_mfma_f32_16x16x32_f16(pf1, v1, oacc[rg][cb], 0, 0, 0);
      }
    }
  }

  #pragma unroll
  for (int rg = 0; rg < 2; ++rg)
    #pragma unroll
    for (int r = 0; r < 4; ++r) {
      int ri = w * 32 + rg * 16 + q4 * 4 + r;
      if (i0 + ri < 260) continue;  // rows 256..259 written by early path
      float e0 = __expf(-m_r[rg][r]);
      float inv = 1.f / l_r[rg][r];
      #pragma unroll
      for (int cb = 0; cb < 4; ++cb) {
        int col = cb * 16 + l15;
        float ol = (oacc[rg][cb][r] + e0 * svg_s[col]) * inv;
        float og = 0.f;
        #pragma unroll
        for (int g = 0; g < 4; ++g) og += pg_s[g][ri] * (float)vg_s[g][col];
        out[(size_t)(i0 + ri) * DMODEL + hb + col] = (_Float16)(ol + og);
      }
    }
}

// ---------------- launcher ----------------
extern "C" void kernel_launch(void* const* d_in, const int* in_sizes, int n_in,
                              void* d_out, int out_size, void* d_ws, size_t ws_size,
                              hipStream_t stream) {
  const float* x     = (const float*)d_in[0];
  const float* cos_t = (const float*)d_in[1];
  const float* sin_t = (const float*)d_in[2];
  const int*   pos   = (const int*)d_in[3];
  const float* Wqs   = (const float*)d_in[4];
  const float* Wks   = (const float*)d_in[5];
  const float* Wvs   = (const float*)d_in[6];
  const float* Wkg   = (const float*)d_in[8];
  const float* Wvg   = (const float*)d_in[9];
  const float* Wo    = (const float*)d_in[10];
  float* out = (float*)d_out;

  char* ws = (char*)d_ws;
  _Float16* xh   = (_Float16*)(ws);                 //  4 MB  dead after proj-gemm
  _Float16* wcat = (_Float16*)(ws + (4u << 20));    // 10 MB  dead after proj-gemm
  _Float16* wot  = (_Float16*)(ws + (14u << 20));   //  2 MB  live till out-gemm
  _Float16* proj = (_Float16*)(ws + (16u << 20));   // 20 MB  dead after attn
  _Float16* attn = (_Float16*)(ws + (36u << 20));   //  4 MB
  float* p0 = (float*)(ws);                         //  8 MB  overlays dead xh/wcat
  float* p1 = (float*)(ws + (16u << 20));           //  8 MB  overlays dead proj

  k_prep<<<2560, 256, 0, stream>>>(x, Wqs, Wks, Wvs, Wkg, Wvg, Wo, xh, wcat, wot);
  // sparse proj GEMM: 384 blocks q|k|v (all M) + 16 blocks kg|vg (m0=0 only)
  k_gemm128b<true, true, true><<<400, 256, 0, stream>>>(
      xh, wcat, proj, nullptr, nullptr, cos_t, sin_t, pos, SEQ, PW, DMODEL, DMODEL);
  k_attn<<<dim3(79, NHEADS), 256, 0, stream>>>(proj, attn);
  k_gemm128b<false, false, false><<<dim3(16, 8, 2), 256, 0, stream>>>(
      attn, wot, nullptr, p0, p1, cos_t, sin_t, pos, SEQ, DMODEL, DMODEL, 512);
  k_reduce<<<SEQ * DMODEL / 1024, 256, 0, stream>>>(p0, p1, out);
}

// Round 10
// 181.266 us; speedup vs baseline: 1.0839x; 1.0839x over previous
//
#include <hip/hip_runtime.h>

typedef _Float16 half8 __attribute__((ext_vector_type(8)));
typedef float floatx4 __attribute__((ext_vector_type(4)));

#define SEQ 2048
#define DMODEL 1024
#define NHEADS 16
#define HEADDIM 64
#define PW 5120   // proj row width: q|k|v|kg|vg

// ---------------- fused prep: x fp32->fp16 + 6 weight transposes ----------------
__global__ __launch_bounds__(256) void k_prep(
    const float* __restrict__ x,
    const float* __restrict__ w0, const float* __restrict__ w1, const float* __restrict__ w2,
    const float* __restrict__ w3, const float* __restrict__ w4, const float* __restrict__ w5,
    _Float16* __restrict__ xh, _Float16* __restrict__ wcat, _Float16* __restrict__ wot) {
  const int tid = threadIdx.x;
  const int b = blockIdx.x;
  if (b < 1024) {
    int base = b * 2048 + tid * 8;
    floatx4 f0 = *(const floatx4*)(x + base);
    floatx4 f1 = *(const floatx4*)(x + base + 4);
    half8 h;
    #pragma unroll
    for (int e = 0; e < 4; ++e) { h[e] = (_Float16)f0[e]; h[e + 4] = (_Float16)f1[e]; }
    *(half8*)(xh + base) = h;
    return;
  }
  __shared__ _Float16 T[64][72];
  int t = b - 1024;
  int z = t >> 8;
  int tile = t & 255;
  int k0 = (tile >> 4) * 64, n0 = (tile & 15) * 64;
  const float* W = (z == 0) ? w0 : (z == 1) ? w1 : (z == 2) ? w2
                 : (z == 3) ? w3 : (z == 4) ? w4 : w5;
  _Float16* dst = (z < 5) ? (wcat + (size_t)z * 1024 * 1024) : wot;

  int lr = tid >> 2, c0 = (tid & 3) * 16;
  #pragma unroll
  for (int i = 0; i < 4; ++i) {
    floatx4 f = *(const floatx4*)(W + (size_t)(k0 + lr) * DMODEL + n0 + c0 + i * 4);
    #pragma unroll
    for (int e = 0; e < 4; ++e) T[c0 + i * 4 + e][lr] = (_Float16)f[e];
  }
  __syncthreads();
  int nr = tid >> 2, s0 = (tid & 3) * 16;
  #pragma unroll
  for (int i = 0; i < 2; ++i) {
    half8 h = *(const half8*)&T[nr][s0 + i * 8];
    *(half8*)(dst + (size_t)(n0 + nr) * DMODEL + k0 + s0 + i * 8) = h;
  }
}

// ---------------- 128x128 MFMA GEMM, BK=128, global_load_lds + XOR swizzle ----------------
// SPARSE (proj path): 400 blocks — b<384 full q|k|v; b>=384 kg|vg at m0=0 only.
// HALF_OUT: fp16 to Cv (+ fused RoPE for n0<2048). !HALF_OUT: fp32 split-K partials.
template <bool HALF_OUT, bool FUSE_ROPE, bool SPARSE>
__global__ __launch_bounds__(256, 2) void k_gemm128b(
    const _Float16* __restrict__ A, const _Float16* __restrict__ Bt,
    void* __restrict__ Cv, float* __restrict__ Cp0, float* __restrict__ Cp1,
    const float* __restrict__ cos_t, const float* __restrict__ sin_t,
    const int* __restrict__ pos, int M, int N, int K, int kLen) {
  __shared__ _Float16 As[128][128];
  __shared__ _Float16 Bs[128][128];
  const int tid = threadIdx.x;
  const int lane = tid & 63;
  const int w = tid >> 6;
  const int wm = (w >> 1) * 64;
  const int wn = (w & 1) * 64;
  const int l15 = lane & 15;
  const int q4 = lane >> 4;
  int m0, n0, kStart;
  if (SPARSE) {
    int b = blockIdx.x;
    if (b < 384) { m0 = (b & 15) * 128; n0 = (b >> 4) * 128; }
    else         { m0 = 0;              n0 = 3072 + (b - 384) * 128; }
    kStart = 0;
  } else {
    m0 = blockIdx.x * 128;
    n0 = blockIdx.y * 128;
    kStart = blockIdx.z * kLen;
  }

  floatx4 acc[4][4];
  #pragma unroll
  for (int i = 0; i < 4; ++i)
    #pragma unroll
    for (int j = 0; j < 4; ++j) acc[i][j] = (floatx4){0.f, 0.f, 0.f, 0.f};

  _Float16* asBase = &As[0][0];
  _Float16* bsBase = &Bs[0][0];
  const int swz = l15 & 7;

  for (int k0 = kStart; k0 < kStart + kLen; k0 += 128) {
    __syncthreads();
    #pragma unroll
    for (int it = 0; it < 8; ++it) {
      int c = it * 256 + tid;
      int r = c >> 4, cc = c & 15;
      int g = cc ^ (r & 7);
      __builtin_amdgcn_global_load_lds(
          (const __attribute__((address_space(1))) void*)(A + (size_t)(m0 + r) * K + k0 + g * 8),
          (__attribute__((address_space(3))) void*)(asBase + (it * 256 + w * 64) * 8),
          16, 0, 0);
      __builtin_amdgcn_global_load_lds(
          (const __attribute__((address_space(1))) void*)(Bt + (size_t)(n0 + r) * K + k0 + g * 8),
          (__attribute__((address_space(3))) void*)(bsBase + (it * 256 + w * 64) * 8),
          16, 0, 0);
    }
    __syncthreads();

    #pragma unroll
    for (int kk = 0; kk < 4; ++kk) {
      int q = kk * 4 + q4;
      half8 af[4], bf[4];
      #pragma unroll
      for (int t = 0; t < 4; ++t) {
        int ar = wm + t * 16 + l15;
        af[t] = *(const half8*)(asBase + (size_t)ar * 128 + ((q ^ swz) * 8));
        int br = wn + t * 16 + l15;
        bf[t] = *(const half8*)(bsBase + (size_t)br * 128 + ((q ^ swz) * 8));
      }
      #pragma unroll
      for (int i = 0; i < 4; ++i)
        #pragma unroll
        for (int j = 0; j < 4; ++j)
          acc[i][j] = __builtin_amdgcn_mfma_f32_16x16x32_f16(af[i], bf[j], acc[i][j], 0, 0, 0);
    }
  }

  float* P = HALF_OUT ? nullptr : ((!SPARSE && blockIdx.z) ? Cp1 : Cp0);
  #pragma unroll
  for (int tm = 0; tm < 4; ++tm) {
    #pragma unroll
    for (int r = 0; r < 4; ++r) {
      int row = m0 + wm + tm * 16 + q4 * 4 + r;
      float v[4];
      #pragma unroll
      for (int tn = 0; tn < 4; ++tn) v[tn] = acc[tm][tn][r];
      if (FUSE_ROPE && n0 < 2048) {
        int p = pos[row];
        #pragma unroll
        for (int tn = 0; tn < 2; ++tn) {
          int d = tn * 16 + l15;
          float a = acc[tm][tn][r];
          float bvv = acc[tm][tn + 2][r];
          float c1 = cos_t[p * 64 + d],      s1 = sin_t[p * 64 + d];
          float c2 = cos_t[p * 64 + d + 32], s2 = sin_t[p * 64 + d + 32];
          v[tn]     = a * c1 - bvv * s1;
          v[tn + 2] = bvv * c2 + a * s2;
        }
      }
      #pragma unroll
      for (int tn = 0; tn < 4; ++tn) {
        int col = n0 + wn + tn * 16 + l15;
        if (HALF_OUT)
          ((_Float16*)Cv)[(size_t)row * N + col] = (_Float16)v[tn];
        else
          P[(size_t)row * N + col] = v[tn];
      }
    }
  }
}

// ---------------- split-K reduce: out = p0 + p1 (fp32) ----------------
__global__ __launch_bounds__(256) void k_reduce(const float* __restrict__ p0,
                                                const float* __restrict__ p1,
                                                float* __restrict__ out) {
  int i = (blockIdx.x * 256 + threadIdx.x) * 4;
  floatx4 a = *(const floatx4*)(p0 + i);
  floatx4 b = *(const floatx4*)(p1 + i);
  *(floatx4*)(out + i) = a + b;
}

// ---------------- merged attention: BM=128, 6 chunks of 64, lean LDS ----------------
// R9 kernel with ONE change: __launch_bounds__(256, 2) — the (256,4) cap forced
// VGPR=64 and spilled (R9: WRITE_SIZE 12.6 MB vs 4 MB real output). Occupancy is
// irrelevant here (224 flash blocks on 256 CUs, all co-resident); registers are not.
__global__ __launch_bounds__(256, 2) void k_attn(const _Float16* __restrict__ proj,
                                                 _Float16* __restrict__ out) {
  const int tid = threadIdx.x;
  const int hb = blockIdx.y * 64;

  if (blockIdx.x >= 14) {
    // ---- early rows (absorbed-1e9: uniform average over in-window global cols) ----
    const int i = (blockIdx.x - 14) * 4 + (tid >> 6);
    const int lane = tid & 63;
    const float scale = 0.125f;
    float qv = (float)proj[(size_t)i * PW + hb + lane];
    float sg[4];
    #pragma unroll
    for (int g = 0; g < 4; ++g) {
      float kgv = (float)proj[(size_t)g * PW + 3072 + hb + lane];
      float v = qv * kgv;
      #pragma unroll
      for (int off = 32; off; off >>= 1) v += __shfl_xor(v, off, 64);
      sg[g] = v * scale;
    }
    float mg = fmaxf(fmaxf(sg[0], sg[1]), fmaxf(sg[2], sg[3]));
    float dg = 0.f, og = 0.f;
    #pragma unroll
    for (int g = 0; g < 4; ++g) {
      float p = __expf(sg[g] - mg);
      dg += p;
      og += p * (float)proj[(size_t)g * PW + 4096 + hb + lane];
    }
    og /= dg;
    int jmin = (i >= 256) ? (i - 256) : 0;
    int jmax = (i < 3) ? i : 3;
    float acc = 0.f;
    for (int j = jmin; j <= jmax; ++j)
      acc += (float)proj[(size_t)j * PW + 2048 + hb + lane];
    float ol = acc / (float)(jmax - jmin + 1);
    out[(size_t)i * DMODEL + hb + lane] = (_Float16)(ol + og);
    return;
  }

  const int i0 = 256 + blockIdx.x * 128;
  const int jlo = i0 - 256;
  const int lane = tid & 63;
  const int w = tid >> 6;
  const int l15 = lane & 15;
  const int q4 = lane >> 4;

  __shared__ _Float16 Kc[64][72];          //  9.0 KB
  __shared__ _Float16 VtcB[64 * 72 + 64];  //  9.1 KB grouped-pad layout
  __shared__ _Float16 Ps[128][72];         // 18.0 KB
  __shared__ _Float16 kg_s[4][64];
  __shared__ _Float16 vg_s[4][64];
  __shared__ float svg_s[64];
  __shared__ float pg_s[4][128];
  #define VTI(d, j) ((d) * 72 + ((d) >> 3) * 8 + (j))

  // ---- stage global k/v + sum of in-window-zero-score v rows ----
  {
    int g = tid >> 6, c2 = tid & 63;
    kg_s[g][c2] = proj[(size_t)g * PW + 3072 + hb + c2];
    vg_s[g][c2] = proj[(size_t)g * PW + 4096 + hb + c2];
    if (tid < 64) {
      float s = 0.f;
      #pragma unroll
      for (int g2 = 0; g2 < 4; ++g2) s += (float)proj[(size_t)g2 * PW + 2048 + hb + tid];
      svg_s[tid] = s;
    }
  }
  __syncthreads();

  // ---- global-attention probabilities for 128 rows (Q direct from global) ----
  #pragma unroll
  for (int pass = 0; pass < 2; ++pass) {
    int ro = pass * 64 + w * 16 + (lane >> 2);
    int part = lane & 3;
    const _Float16* qrow = proj + (size_t)(i0 + ro) * PW + hb + part * 16;
    float sg[4];
    #pragma unroll
    for (int g = 0; g < 4; ++g) {
      float acc = 0.f;
      #pragma unroll
      for (int u = 0; u < 16; ++u)
        acc += (float)qrow[u] * (float)kg_s[g][part * 16 + u];
      acc += __shfl_xor(acc, 1, 64);
      acc += __shfl_xor(acc, 2, 64);
      sg[g] = acc * 0.125f;
    }
    float mg = fmaxf(fmaxf(sg[0], sg[1]), fmaxf(sg[2], sg[3]));
    float dg = 0.f;
    #pragma unroll
    for (int g = 0; g < 4; ++g) dg += __expf(sg[g] - mg);
    pg_s[part][ro] = __expf(sg[part] - mg) / dg;
  }

  // Q A-frags direct from global (wave-private rows, registers only)
  half8 qf[2][2];
  #pragma unroll
  for (int rg = 0; rg < 2; ++rg) {
    const _Float16* qp = proj + (size_t)(i0 + w * 32 + rg * 16 + l15) * PW + hb;
    qf[rg][0] = *(const half8*)(qp + q4 * 8);
    qf[rg][1] = *(const half8*)(qp + 32 + q4 * 8);
  }

  float m_r[2][4], l_r[2][4];
  floatx4 oacc[2][4];
  #pragma unroll
  for (int rg = 0; rg < 2; ++rg)
    #pragma unroll
    for (int cb = 0; cb < 4; ++cb) {
      oacc[rg][cb] = (floatx4){0.f, 0.f, 0.f, 0.f};
      m_r[rg][cb] = 0.f;
      l_r[rg][cb] = 4.f;   // 4 global cols with fp32 score exactly 0
    }

  for (int cc = 0; cc < 6; ++cc) {
    const int jbase = jlo + cc * 64;
    __syncthreads();  // prior-iter Kc/Vtc reads done
    // K chunk: 64 rows x 64 halfs, plain half8 loads
    #pragma unroll
    for (int rep = 0; rep < 2; ++rep) {
      int c = tid + rep * 256;
      int r = c >> 3, q = c & 7;
      *(half8*)&Kc[r][q * 8] =
          *(const half8*)(proj + (size_t)(jbase + r) * PW + 1024 + hb + q * 8);
    }
    // V chunk transposed: half8 global loads, grouped-pad scalar scatter (conflict-free)
    #pragma unroll
    for (int it = 0; it < 2; ++it) {
      int idx = it * 256 + tid;
      int j = (idx & 7) + ((idx >> 6) << 3);
      int d0 = ((idx >> 3) & 7) * 8;
      half8 vv = *(const half8*)(proj + (size_t)(jbase + j) * PW + 2048 + hb + d0);
      #pragma unroll
      for (int e = 0; e < 8; ++e) VtcB[VTI(d0 + e, j)] = vv[e];
    }
    __syncthreads();

    #pragma unroll
    for (int rg = 0; rg < 2; ++rg) {
      // QK^T: 4 col-blocks of 16
      float sc[4][4];
      #pragma unroll
      for (int cb = 0; cb < 4; ++cb) {
        half8 b0 = *(const half8*)&Kc[cb * 16 + l15][q4 * 8];
        half8 b1 = *(const half8*)&Kc[cb * 16 + l15][32 + q4 * 8];
        floatx4 a = (floatx4){0.f, 0.f, 0.f, 0.f};
        a = __builtin_amdgcn_mfma_f32_16x16x32_f16(qf[rg][0], b0, a, 0, 0, 0);
        a = __builtin_amdgcn_mfma_f32_16x16x32_f16(qf[rg][1], b1, a, 0, 0, 0);
        #pragma unroll
        for (int r = 0; r < 4; ++r) sc[cb][r] = a[r];
      }

      // mask + online softmax
      #pragma unroll
      for (int r = 0; r < 4; ++r) {
        int ri = w * 32 + rg * 16 + q4 * 4 + r;
        float rowmax = -1e30f;
        #pragma unroll
        for (int cb = 0; cb < 4; ++cb) {
          int jjg = cc * 64 + cb * 16 + l15;
          bool valid = (jjg >= ri) && (jjg <= ri + 256);
          float s = valid ? sc[cb][r] * 0.125f : -1e30f;
          sc[cb][r] = s;
          rowmax = fmaxf(rowmax, s);
        }
        #pragma unroll
        for (int off = 1; off < 16; off <<= 1)
          rowmax = fmaxf(rowmax, __shfl_xor(rowmax, off, 64));
        float m_new = fmaxf(m_r[rg][r], rowmax);
        float alpha = __expf(m_r[rg][r] - m_new);
        float rs = 0.f;
        #pragma unroll
        for (int cb = 0; cb < 4; ++cb) {
          float p = __expf(sc[cb][r] - m_new);
          Ps[ri][cb * 16 + l15] = (_Float16)p;
          rs += p;
        }
        #pragma unroll
        for (int off = 1; off < 16; off <<= 1) rs += __shfl_xor(rs, off, 64);
        l_r[rg][r] = l_r[rg][r] * alpha + rs;
        m_r[rg][r] = m_new;
        #pragma unroll
        for (int cb = 0; cb < 4; ++cb) oacc[rg][cb][r] *= alpha;
      }

      // PV: A=P (own rows, same-wave), B=V^T (grouped-pad reads, 16B-aligned)
      int prow = w * 32 + rg * 16 + l15;
      half8 pf0 = *(const half8*)&Ps[prow][q4 * 8];
      half8 pf1 = *(const half8*)&Ps[prow][32 + q4 * 8];
      #pragma unroll
      for (int cb = 0; cb < 4; ++cb) {
        int vd = cb * 16 + l15;
        half8 v0 = *(const half8*)&VtcB[VTI(vd, 0) + q4 * 8];
        half8 v1 = *(const half8*)&VtcB[VTI(vd, 0) + 32 + q4 * 8];
        oacc[rg][cb] = __builtin_amdgcn_mfma_f32_16x16x32_f16(pf0, v0, oacc[rg][cb], 0, 0, 0);
        oacc[rg][cb] = __builtin_amdgcn_mfma_f32_16x16x32_f16(pf1, v1, oacc[rg][cb], 0, 0, 0);
      }
    }
  }

  #pragma unroll
  for (int rg = 0; rg < 2; ++rg)
    #pragma unroll
    for (int r = 0; r < 4; ++r) {
      int ri = w * 32 + rg * 16 + q4 * 4 + r;
      if (i0 + ri < 260) continue;  // rows 256..259 written by early path
      float e0 = __expf(-m_r[rg][r]);
      float inv = 1.f / l_r[rg][r];
      #pragma unroll
      for (int cb = 0; cb < 4; ++cb) {
        int col = cb * 16 + l15;
        float ol = (oacc[rg][cb][r] + e0 * svg_s[col]) * inv;
        float og = 0.f;
        #pragma unroll
        for (int g = 0; g < 4; ++g) og += pg_s[g][ri] * (float)vg_s[g][col];
        out[(size_t)(i0 + ri) * DMODEL + hb + col] = (_Float16)(ol + og);
      }
    }
}

// ---------------- launcher ----------------
extern "C" void kernel_launch(void* const* d_in, const int* in_sizes, int n_in,
                              void* d_out, int out_size, void* d_ws, size_t ws_size,
                              hipStream_t stream) {
  const float* x     = (const float*)d_in[0];
  const float* cos_t = (const float*)d_in[1];
  const float* sin_t = (const float*)d_in[2];
  const int*   pos   = (const int*)d_in[3];
  const float* Wqs   = (const float*)d_in[4];
  const float* Wks   = (const float*)d_in[5];
  const float* Wvs   = (const float*)d_in[6];
  const float* Wkg   = (const float*)d_in[8];
  const float* Wvg   = (const float*)d_in[9];
  const float* Wo    = (const float*)d_in[10];
  float* out = (float*)d_out;

  char* ws = (char*)d_ws;
  _Float16* xh   = (_Float16*)(ws);                 //  4 MB  dead after proj-gemm
  _Float16* wcat = (_Float16*)(ws + (4u << 20));    // 10 MB  dead after proj-gemm
  _Float16* wot  = (_Float16*)(ws + (14u << 20));   //  2 MB  live till out-gemm
  _Float16* proj = (_Float16*)(ws + (16u << 20));   // 20 MB  dead after attn
  _Float16* attn = (_Float16*)(ws + (36u << 20));   //  4 MB
  float* p0 = (float*)(ws);                         //  8 MB  overlays dead xh/wcat
  float* p1 = (float*)(ws + (16u << 20));           //  8 MB  overlays dead proj

  k_prep<<<2560, 256, 0, stream>>>(x, Wqs, Wks, Wvs, Wkg, Wvg, Wo, xh, wcat, wot);
  // sparse proj GEMM: 384 blocks q|k|v (all M) + 16 blocks kg|vg (m0=0 only)
  k_gemm128b<true, true, true><<<400, 256, 0, stream>>>(
      xh, wcat, proj, nullptr, nullptr, cos_t, sin_t, pos, SEQ, PW, DMODEL, DMODEL);
  k_attn<<<dim3(79, NHEADS), 256, 0, stream>>>(proj, attn);
  k_gemm128b<false, false, false><<<dim3(16, 8, 2), 256, 0, stream>>>(
      attn, wot, nullptr, p0, p1, cos_t, sin_t, pos, SEQ, DMODEL, DMODEL, 512);
  k_reduce<<<SEQ * DMODEL / 1024, 256, 0, stream>>>(p0, p1, out);
}

// Round 11
// 176.714 us; speedup vs baseline: 1.1118x; 1.0258x over previous
//
#include <hip/hip_runtime.h>

typedef _Float16 half8 __attribute__((ext_vector_type(8)));
typedef float floatx4 __attribute__((ext_vector_type(4)));

#define SEQ 2048
#define DMODEL 1024
#define NHEADS 16
#define HEADDIM 64
#define PW 5120   // proj row width: q|k|v|kg|vg

// ---------------- fused prep: x fp32->fp16 + 6 weight transposes ----------------
__global__ __launch_bounds__(256) void k_prep(
    const float* __restrict__ x,
    const float* __restrict__ w0, const float* __restrict__ w1, const float* __restrict__ w2,
    const float* __restrict__ w3, const float* __restrict__ w4, const float* __restrict__ w5,
    _Float16* __restrict__ xh, _Float16* __restrict__ wcat, _Float16* __restrict__ wot) {
  const int tid = threadIdx.x;
  const int b = blockIdx.x;
  if (b < 1024) {
    int base = b * 2048 + tid * 8;
    floatx4 f0 = *(const floatx4*)(x + base);
    floatx4 f1 = *(const floatx4*)(x + base + 4);
    half8 h;
    #pragma unroll
    for (int e = 0; e < 4; ++e) { h[e] = (_Float16)f0[e]; h[e + 4] = (_Float16)f1[e]; }
    *(half8*)(xh + base) = h;
    return;
  }
  __shared__ _Float16 T[64][72];
  int t = b - 1024;
  int z = t >> 8;
  int tile = t & 255;
  int k0 = (tile >> 4) * 64, n0 = (tile & 15) * 64;
  const float* W = (z == 0) ? w0 : (z == 1) ? w1 : (z == 2) ? w2
                 : (z == 3) ? w3 : (z == 4) ? w4 : w5;
  _Float16* dst = (z < 5) ? (wcat + (size_t)z * 1024 * 1024) : wot;

  int lr = tid >> 2, c0 = (tid & 3) * 16;
  #pragma unroll
  for (int i = 0; i < 4; ++i) {
    floatx4 f = *(const floatx4*)(W + (size_t)(k0 + lr) * DMODEL + n0 + c0 + i * 4);
    #pragma unroll
    for (int e = 0; e < 4; ++e) T[c0 + i * 4 + e][lr] = (_Float16)f[e];
  }
  __syncthreads();
  int nr = tid >> 2, s0 = (tid & 3) * 16;
  #pragma unroll
  for (int i = 0; i < 2; ++i) {
    half8 h = *(const half8*)&T[nr][s0 + i * 8];
    *(half8*)(dst + (size_t)(n0 + nr) * DMODEL + k0 + s0 + i * 8) = h;
  }
}

// ---------------- 128x128 MFMA GEMM, BK=128, global_load_lds + XOR swizzle ----------------
// SPARSE (proj path): 400 blocks — b<384 full q|k|v; b>=384 kg|vg at m0=0 only.
// HALF_OUT: fp16 to Cv (+ fused RoPE for n0<2048). !HALF_OUT: fp32 split-K partials.
template <bool HALF_OUT, bool FUSE_ROPE, bool SPARSE>
__global__ __launch_bounds__(256, 2) void k_gemm128b(
    const _Float16* __restrict__ A, const _Float16* __restrict__ Bt,
    void* __restrict__ Cv, float* __restrict__ Cp0, float* __restrict__ Cp1,
    const float* __restrict__ cos_t, const float* __restrict__ sin_t,
    const int* __restrict__ pos, int M, int N, int K, int kLen) {
  __shared__ _Float16 As[128][128];
  __shared__ _Float16 Bs[128][128];
  const int tid = threadIdx.x;
  const int lane = tid & 63;
  const int w = tid >> 6;
  const int wm = (w >> 1) * 64;
  const int wn = (w & 1) * 64;
  const int l15 = lane & 15;
  const int q4 = lane >> 4;
  int m0, n0, kStart;
  if (SPARSE) {
    int b = blockIdx.x;
    if (b < 384) { m0 = (b & 15) * 128; n0 = (b >> 4) * 128; }
    else         { m0 = 0;              n0 = 3072 + (b - 384) * 128; }
    kStart = 0;
  } else {
    m0 = blockIdx.x * 128;
    n0 = blockIdx.y * 128;
    kStart = blockIdx.z * kLen;
  }

  floatx4 acc[4][4];
  #pragma unroll
  for (int i = 0; i < 4; ++i)
    #pragma unroll
    for (int j = 0; j < 4; ++j) acc[i][j] = (floatx4){0.f, 0.f, 0.f, 0.f};

  _Float16* asBase = &As[0][0];
  _Float16* bsBase = &Bs[0][0];
  const int swz = l15 & 7;

  for (int k0 = kStart; k0 < kStart + kLen; k0 += 128) {
    __syncthreads();
    #pragma unroll
    for (int it = 0; it < 8; ++it) {
      int c = it * 256 + tid;
      int r = c >> 4, cc = c & 15;
      int g = cc ^ (r & 7);
      __builtin_amdgcn_global_load_lds(
          (const __attribute__((address_space(1))) void*)(A + (size_t)(m0 + r) * K + k0 + g * 8),
          (__attribute__((address_space(3))) void*)(asBase + (it * 256 + w * 64) * 8),
          16, 0, 0);
      __builtin_amdgcn_global_load_lds(
          (const __attribute__((address_space(1))) void*)(Bt + (size_t)(n0 + r) * K + k0 + g * 8),
          (__attribute__((address_space(3))) void*)(bsBase + (it * 256 + w * 64) * 8),
          16, 0, 0);
    }
    __syncthreads();

    #pragma unroll
    for (int kk = 0; kk < 4; ++kk) {
      int q = kk * 4 + q4;
      half8 af[4], bf[4];
      #pragma unroll
      for (int t = 0; t < 4; ++t) {
        int ar = wm + t * 16 + l15;
        af[t] = *(const half8*)(asBase + (size_t)ar * 128 + ((q ^ swz) * 8));
        int br = wn + t * 16 + l15;
        bf[t] = *(const half8*)(bsBase + (size_t)br * 128 + ((q ^ swz) * 8));
      }
      #pragma unroll
      for (int i = 0; i < 4; ++i)
        #pragma unroll
        for (int j = 0; j < 4; ++j)
          acc[i][j] = __builtin_amdgcn_mfma_f32_16x16x32_f16(af[i], bf[j], acc[i][j], 0, 0, 0);
    }
  }

  float* P = HALF_OUT ? nullptr : ((!SPARSE && blockIdx.z) ? Cp1 : Cp0);
  #pragma unroll
  for (int tm = 0; tm < 4; ++tm) {
    #pragma unroll
    for (int r = 0; r < 4; ++r) {
      int row = m0 + wm + tm * 16 + q4 * 4 + r;
      float v[4];
      #pragma unroll
      for (int tn = 0; tn < 4; ++tn) v[tn] = acc[tm][tn][r];
      if (FUSE_ROPE && n0 < 2048) {
        int p = pos[row];
        #pragma unroll
        for (int tn = 0; tn < 2; ++tn) {
          int d = tn * 16 + l15;
          float a = acc[tm][tn][r];
          float bvv = acc[tm][tn + 2][r];
          float c1 = cos_t[p * 64 + d],      s1 = sin_t[p * 64 + d];
          float c2 = cos_t[p * 64 + d + 32], s2 = sin_t[p * 64 + d + 32];
          v[tn]     = a * c1 - bvv * s1;
          v[tn + 2] = bvv * c2 + a * s2;
        }
      }
      #pragma unroll
      for (int tn = 0; tn < 4; ++tn) {
        int col = n0 + wn + tn * 16 + l15;
        if (HALF_OUT)
          ((_Float16*)Cv)[(size_t)row * N + col] = (_Float16)v[tn];
        else
          P[(size_t)row * N + col] = v[tn];
      }
    }
  }
}

// ---------------- split-K reduce: out = p0 + p1 (fp32) ----------------
__global__ __launch_bounds__(256) void k_reduce(const float* __restrict__ p0,
                                                const float* __restrict__ p1,
                                                float* __restrict__ out) {
  int i = (blockIdx.x * 256 + threadIdx.x) * 4;
  floatx4 a = *(const floatx4*)(p0 + i);
  floatx4 b = *(const floatx4*)(p1 + i);
  *(floatx4*)(out + i) = a + b;
}

// ---------------- merged attention: R6 structure + grouped-pad V^T ONLY ----------------
// = the 172-us R6 kernel (Qs staged in LDS; BM=128; 6 chunks of 64) with one change:
// V^T layout VTI(d,j) = d*72 + (d>>3)*8 + j. R6's Vtc[64][72] scatter had 8-row group
// stride 288 words = 0 mod 32 -> 8-way conflicts; grouped-pad gives 292 = 4 mod 32,
// tiling all banks (verified correct + conflict-reducing in R10).
__global__ __launch_bounds__(256, 2) void k_attn(const _Float16* __restrict__ proj,
                                                 _Float16* __restrict__ out) {
  const int tid = threadIdx.x;
  const int hb = blockIdx.y * 64;

  if (blockIdx.x >= 14) {
    // ---- early rows (absorbed-1e9: uniform average over in-window global cols) ----
    const int i = (blockIdx.x - 14) * 4 + (tid >> 6);
    const int lane = tid & 63;
    const float scale = 0.125f;
    float qv = (float)proj[(size_t)i * PW + hb + lane];
    float sg[4];
    #pragma unroll
    for (int g = 0; g < 4; ++g) {
      float kgv = (float)proj[(size_t)g * PW + 3072 + hb + lane];
      float v = qv * kgv;
      #pragma unroll
      for (int off = 32; off; off >>= 1) v += __shfl_xor(v, off, 64);
      sg[g] = v * scale;
    }
    float mg = fmaxf(fmaxf(sg[0], sg[1]), fmaxf(sg[2], sg[3]));
    float dg = 0.f, og = 0.f;
    #pragma unroll
    for (int g = 0; g < 4; ++g) {
      float p = __expf(sg[g] - mg);
      dg += p;
      og += p * (float)proj[(size_t)g * PW + 4096 + hb + lane];
    }
    og /= dg;
    int jmin = (i >= 256) ? (i - 256) : 0;
    int jmax = (i < 3) ? i : 3;
    float acc = 0.f;
    for (int j = jmin; j <= jmax; ++j)
      acc += (float)proj[(size_t)j * PW + 2048 + hb + lane];
    float ol = acc / (float)(jmax - jmin + 1);
    out[(size_t)i * DMODEL + hb + lane] = (_Float16)(ol + og);
    return;
  }

  const int i0 = 256 + blockIdx.x * 128;
  const int jlo = i0 - 256;
  const int lane = tid & 63;
  const int w = tid >> 6;
  const int l15 = lane & 15;
  const int q4 = lane >> 4;

  __shared__ _Float16 Qs[128][72];         // 18.0 KB (R6 idiom: Q staged once)
  __shared__ _Float16 Kc[64][72];          //  9.0 KB
  __shared__ _Float16 VtcB[64 * 72 + 64];  //  9.1 KB grouped-pad layout
  __shared__ _Float16 Ps[128][72];         // 18.0 KB
  __shared__ _Float16 kg_s[4][64];
  __shared__ _Float16 vg_s[4][64];
  __shared__ float svg_s[64];
  __shared__ float pg_s[4][128];
  #define VTI(d, j) ((d) * 72 + ((d) >> 3) * 8 + (j))

  // ---- stage Q tile + global k/v + sum of in-window-zero-score v rows ----
  #pragma unroll
  for (int rep = 0; rep < 4; ++rep) {
    int c = tid + rep * 256;
    int r = c >> 3, q = c & 7;
    *(half8*)&Qs[r][q * 8] = *(const half8*)(proj + (size_t)(i0 + r) * PW + hb + q * 8);
  }
  {
    int g = tid >> 6, c2 = tid & 63;
    kg_s[g][c2] = proj[(size_t)g * PW + 3072 + hb + c2];
    vg_s[g][c2] = proj[(size_t)g * PW + 4096 + hb + c2];
    if (tid < 64) {
      float s = 0.f;
      #pragma unroll
      for (int g2 = 0; g2 < 4; ++g2) s += (float)proj[(size_t)g2 * PW + 2048 + hb + tid];
      svg_s[tid] = s;
    }
  }
  __syncthreads();

  // ---- global-attention probabilities for 128 rows (two 64-row passes, from Qs) ----
  #pragma unroll
  for (int pass = 0; pass < 2; ++pass) {
    int ro = pass * 64 + w * 16 + (lane >> 2);
    int part = lane & 3;
    float sg[4];
    #pragma unroll
    for (int g = 0; g < 4; ++g) {
      float acc = 0.f;
      #pragma unroll
      for (int u = 0; u < 16; ++u)
        acc += (float)Qs[ro][part * 16 + u] * (float)kg_s[g][part * 16 + u];
      acc += __shfl_xor(acc, 1, 64);
      acc += __shfl_xor(acc, 2, 64);
      sg[g] = acc * 0.125f;
    }
    float mg = fmaxf(fmaxf(sg[0], sg[1]), fmaxf(sg[2], sg[3]));
    float dg = 0.f;
    #pragma unroll
    for (int g = 0; g < 4; ++g) dg += __expf(sg[g] - mg);
    pg_s[part][ro] = __expf(sg[part] - mg) / dg;
  }

  // Q A-frags from LDS (wave w owns rows w*32 .. w*32+31)
  half8 qf[2][2];
  #pragma unroll
  for (int rg = 0; rg < 2; ++rg) {
    int row = w * 32 + rg * 16 + l15;
    qf[rg][0] = *(const half8*)&Qs[row][q4 * 8];
    qf[rg][1] = *(const half8*)&Qs[row][32 + q4 * 8];
  }

  float m_r[2][4], l_r[2][4];
  floatx4 oacc[2][4];
  #pragma unroll
  for (int rg = 0; rg < 2; ++rg)
    #pragma unroll
    for (int cb = 0; cb < 4; ++cb) {
      oacc[rg][cb] = (floatx4){0.f, 0.f, 0.f, 0.f};
      m_r[rg][cb] = 0.f;
      l_r[rg][cb] = 4.f;   // 4 global cols with fp32 score exactly 0
    }

  for (int cc = 0; cc < 6; ++cc) {
    const int jbase = jlo + cc * 64;
    __syncthreads();  // prior-iter Kc/Vtc reads done
    // K chunk: 64 rows x 64 halfs, plain half8 loads
    #pragma unroll
    for (int rep = 0; rep < 2; ++rep) {
      int c = tid + rep * 256;
      int r = c >> 3, q = c & 7;
      *(half8*)&Kc[r][q * 8] =
          *(const half8*)(proj + (size_t)(jbase + r) * PW + 1024 + hb + q * 8);
    }
    // V chunk transposed: half8 global loads, grouped-pad scalar scatter (conflict-free)
    #pragma unroll
    for (int it = 0; it < 2; ++it) {
      int idx = it * 256 + tid;
      int j = (idx & 7) + ((idx >> 6) << 3);
      int d0 = ((idx >> 3) & 7) * 8;
      half8 vv = *(const half8*)(proj + (size_t)(jbase + j) * PW + 2048 + hb + d0);
      #pragma unroll
      for (int e = 0; e < 8; ++e) VtcB[VTI(d0 + e, j)] = vv[e];
    }
    __syncthreads();

    #pragma unroll
    for (int rg = 0; rg < 2; ++rg) {
      // QK^T: 4 col-blocks of 16
      float sc[4][4];
      #pragma unroll
      for (int cb = 0; cb < 4; ++cb) {
        half8 b0 = *(const half8*)&Kc[cb * 16 + l15][q4 * 8];
        half8 b1 = *(const half8*)&Kc[cb * 16 + l15][32 + q4 * 8];
        floatx4 a = (floatx4){0.f, 0.f, 0.f, 0.f};
        a = __builtin_amdgcn_mfma_f32_16x16x32_f16(qf[rg][0], b0, a, 0, 0, 0);
        a = __builtin_amdgcn_mfma_f32_16x16x32_f16(qf[rg][1], b1, a, 0, 0, 0);
        #pragma unroll
        for (int r = 0; r < 4; ++r) sc[cb][r] = a[r];
      }

      // mask + online softmax
      #pragma unroll
      for (int r = 0; r < 4; ++r) {
        int ri = w * 32 + rg * 16 + q4 * 4 + r;
        float rowmax = -1e30f;
        #pragma unroll
        for (int cb = 0; cb < 4; ++cb) {
          int jjg = cc * 64 + cb * 16 + l15;
          bool valid = (jjg >= ri) && (jjg <= ri + 256);
          float s = valid ? sc[cb][r] * 0.125f : -1e30f;
          sc[cb][r] = s;
          rowmax = fmaxf(rowmax, s);
        }
        #pragma unroll
        for (int off = 1; off < 16; off <<= 1)
          rowmax = fmaxf(rowmax, __shfl_xor(rowmax, off, 64));
        float m_new = fmaxf(m_r[rg][r], rowmax);
        float alpha = __expf(m_r[rg][r] - m_new);
        float rs = 0.f;
        #pragma unroll
        for (int cb = 0; cb < 4; ++cb) {
          float p = __expf(sc[cb][r] - m_new);
          Ps[ri][cb * 16 + l15] = (_Float16)p;
          rs += p;
        }
        #pragma unroll
        for (int off = 1; off < 16; off <<= 1) rs += __shfl_xor(rs, off, 64);
        l_r[rg][r] = l_r[rg][r] * alpha + rs;
        m_r[rg][r] = m_new;
        #pragma unroll
        for (int cb = 0; cb < 4; ++cb) oacc[rg][cb][r] *= alpha;
      }

      // PV: A=P (own rows, same-wave), B=V^T (grouped-pad reads, 16B-aligned)
      int prow = w * 32 + rg * 16 + l15;
      half8 pf0 = *(const half8*)&Ps[prow][q4 * 8];
      half8 pf1 = *(const half8*)&Ps[prow][32 + q4 * 8];
      #pragma unroll
      for (int cb = 0; cb < 4; ++cb) {
        int vd = cb * 16 + l15;
        half8 v0 = *(const half8*)&VtcB[VTI(vd, 0) + q4 * 8];
        half8 v1 = *(const half8*)&VtcB[VTI(vd, 0) + 32 + q4 * 8];
        oacc[rg][cb] = __builtin_amdgcn_mfma_f32_16x16x32_f16(pf0, v0, oacc[rg][cb], 0, 0, 0);
        oacc[rg][cb] = __builtin_amdgcn_mfma_f32_16x16x32_f16(pf1, v1, oacc[rg][cb], 0, 0, 0);
      }
    }
  }

  #pragma unroll
  for (int rg = 0; rg < 2; ++rg)
    #pragma unroll
    for (int r = 0; r < 4; ++r) {
      int ri = w * 32 + rg * 16 + q4 * 4 + r;
      if (i0 + ri < 260) continue;  // rows 256..259 written by early path
      float e0 = __expf(-m_r[rg][r]);
      float inv = 1.f / l_r[rg][r];
      #pragma unroll
      for (int cb = 0; cb < 4; ++cb) {
        int col = cb * 16 + l15;
        float ol = (oacc[rg][cb][r] + e0 * svg_s[col]) * inv;
        float og = 0.f;
        #pragma unroll
        for (int g = 0; g < 4; ++g) og += pg_s[g][ri] * (float)vg_s[g][col];
        out[(size_t)(i0 + ri) * DMODEL + hb + col] = (_Float16)(ol + og);
      }
    }
}

// ---------------- launcher ----------------
extern "C" void kernel_launch(void* const* d_in, const int* in_sizes, int n_in,
                              void* d_out, int out_size, void* d_ws, size_t ws_size,
                              hipStream_t stream) {
  const float* x     = (const float*)d_in[0];
  const float* cos_t = (const float*)d_in[1];
  const float* sin_t = (const float*)d_in[2];
  const int*   pos   = (const int*)d_in[3];
  const float* Wqs   = (const float*)d_in[4];
  const float* Wks   = (const float*)d_in[5];
  const float* Wvs   = (const float*)d_in[6];
  const float* Wkg   = (const float*)d_in[8];
  const float* Wvg   = (const float*)d_in[9];
  const float* Wo    = (const float*)d_in[10];
  float* out = (float*)d_out;

  char* ws = (char*)d_ws;
  _Float16* xh   = (_Float16*)(ws);                 //  4 MB  dead after proj-gemm
  _Float16* wcat = (_Float16*)(ws + (4u << 20));    // 10 MB  dead after proj-gemm
  _Float16* wot  = (_Float16*)(ws + (14u << 20));   //  2 MB  live till out-gemm
  _Float16* proj = (_Float16*)(ws + (16u << 20));   // 20 MB  dead after attn
  _Float16* attn = (_Float16*)(ws + (36u << 20));   //  4 MB
  float* p0 = (float*)(ws);                         //  8 MB  overlays dead xh/wcat
  float* p1 = (float*)(ws + (16u << 20));           //  8 MB  overlays dead proj

  k_prep<<<2560, 256, 0, stream>>>(x, Wqs, Wks, Wvs, Wkg, Wvg, Wo, xh, wcat, wot);
  // sparse proj GEMM: 384 blocks q|k|v (all M) + 16 blocks kg|vg (m0=0 only)
  k_gemm128b<true, true, true><<<400, 256, 0, stream>>>(
      xh, wcat, proj, nullptr, nullptr, cos_t, sin_t, pos, SEQ, PW, DMODEL, DMODEL);
  k_attn<<<dim3(79, NHEADS), 256, 0, stream>>>(proj, attn);
  k_gemm128b<false, false, false><<<dim3(16, 8, 2), 256, 0, stream>>>(
      attn, wot, nullptr, p0, p1, cos_t, sin_t, pos, SEQ, DMODEL, DMODEL, 512);
  k_reduce<<<SEQ * DMODEL / 1024, 256, 0, stream>>>(p0, p1, out);
}